// Round 2
// baseline (1607.343 us; speedup 1.0000x reference)
//
#include <hip/hip_runtime.h>
#include <hip/hip_bf16.h>

#define BATCH 16
#define NN 1024
#define MM 1024
#define DD 512

#define LOG2E 1.4426950408889634f
#define LN2f  0.6931471805599453f
#define NEGS  -1.442695e9f   // NEG (-1e9) scaled by log2e; acts as -inf sentinel

typedef __bf16 v8bf __attribute__((ext_vector_type(8)));
typedef __bf16 v4bf __attribute__((ext_vector_type(4)));
typedef float  v4f  __attribute__((ext_vector_type(4)));

// ---------------------------------------------------------------- zero A acc
__global__ void zero_acc(float* a) {
    if (threadIdx.x < BATCH) a[threadIdx.x] = 0.0f;
}

// ------------------------------------------- fp32->bf16 convert + gap-dot
// grid (16 chunks, BATCH, 2 tensors), block 256.
// Each block: 64 rows x 512 cols of one batch of one tensor.
__global__ __launch_bounds__(256) void conv_reduce(
        const float* __restrict__ zx, const float* __restrict__ zy,
        const float* __restrict__ gw,
        __bf16* __restrict__ zxb, __bf16* __restrict__ zyb,
        float* __restrict__ acc) {
    const int chunk = blockIdx.x, b = blockIdx.y, which = blockIdx.z;
    const float* src = which ? zy : zx;
    __bf16* dst = which ? zyb : zxb;
    const float* g = gw + which * DD;
    const size_t base = ((size_t)b * NN + (size_t)chunk * 64) * DD;
    const int t = threadIdx.x;
    const int col = (t * 4) & (DD - 1);
    const float4 gv = *(const float4*)(g + col);
    float sum = 0.0f;
    #pragma unroll 4
    for (int it = 0; it < 32; ++it) {
        size_t off = base + (size_t)it * 1024 + t * 4;
        float4 x = *(const float4*)(src + off);
        sum += x.x * gv.x + x.y * gv.y + x.z * gv.z + x.w * gv.w;
        v4bf o = { (__bf16)x.x, (__bf16)x.y, (__bf16)x.z, (__bf16)x.w };
        *(v4bf*)(dst + off) = o;
    }
    // wave reduce (64 lanes)
    #pragma unroll
    for (int o = 32; o > 0; o >>= 1) sum += __shfl_down(sum, o);
    __shared__ float wsum[4];
    if ((t & 63) == 0) wsum[t >> 6] = sum;
    __syncthreads();
    if (t == 0) {
        float s = wsum[0] + wsum[1] + wsum[2] + wsum[3];
        atomicAdd(acc + b, s * (1.0f / 1024.0f));  // mean over N (=M=1024)
    }
}

// ------------------------------------------------------- bf16 MFMA NT GEMM
// theta[b,i,j] = sum_d zx[b,i,d]*zy[b,j,d].  grid (16,16,BATCH), block 256.
// 64x64 tile, BK=32, 4 waves each computing 16 rows x 64 cols.
__global__ __launch_bounds__(256) void gemm_bt(
        const __bf16* __restrict__ Abf, const __bf16* __restrict__ Bbf,
        float* __restrict__ theta) {
    __shared__ __bf16 As[64 * 40];   // +8 bf16 pad: stride 80B (16B aligned)
    __shared__ __bf16 Bs[64 * 40];
    const int b = blockIdx.z;
    const int i0 = blockIdx.y * 64, j0 = blockIdx.x * 64;
    const __bf16* ap = Abf + ((size_t)b * NN + i0) * DD;
    const __bf16* bp = Bbf + ((size_t)b * MM + j0) * DD;
    const int t = threadIdx.x;
    const int srow = t >> 2, scol = (t & 3) * 8;
    const int lane = t & 63, wave = t >> 6;
    const int mrow = lane & 15, quad = lane >> 4;
    v4f acc[4] = {};
    for (int kk = 0; kk < DD; kk += 32) {
        if (kk) __syncthreads();
        *(v8bf*)&As[srow * 40 + scol] = *(const v8bf*)(ap + (size_t)srow * DD + kk + scol);
        *(v8bf*)&Bs[srow * 40 + scol] = *(const v8bf*)(bp + (size_t)srow * DD + kk + scol);
        __syncthreads();
        v8bf af = *(const v8bf*)&As[(wave * 16 + mrow) * 40 + quad * 8];
        #pragma unroll
        for (int tt = 0; tt < 4; ++tt) {
            v8bf bf = *(const v8bf*)&Bs[(tt * 16 + mrow) * 40 + quad * 8];
            acc[tt] = __builtin_amdgcn_mfma_f32_16x16x32_bf16(af, bf, acc[tt], 0, 0, 0);
        }
    }
    const size_t tb = (size_t)b * NN * MM;
    #pragma unroll
    for (int tt = 0; tt < 4; ++tt) {
        int j = j0 + tt * 16 + mrow;               // C/D: col = lane&15
        #pragma unroll
        for (int r = 0; r < 4; ++r) {
            int i = i0 + wave * 16 + quad * 4 + r; // C/D: row = quad*4+reg
            theta[tb + (size_t)i * MM + j] = acc[tt][r];
        }
    }
}

// --------------------------------------------------- soft-NW wavefront DP
// One block (1024 threads) per batch. Thread i owns V-grid row i+1.
// All values scaled by log2e so lse uses exp2/log2 directly.
__global__ __launch_bounds__(1024) void nw_dp(
        const float* __restrict__ theta, const float* __restrict__ acc,
        const float* __restrict__ gap_b, float* __restrict__ out) {
    const int b = blockIdx.x;
    const int i = threadIdx.x;
    const int lane = i & 63, wave = i >> 6;
    const int i0 = wave * 64;
    const float Ac = (acc[b] + gap_b[0]) * LOG2E;
    const float* row = theta + ((size_t)b * NN + i) * MM;
    float4 blk  = *(const float4*)(row);
    float4 nblk = *(const float4*)(row + 4);
    float v1 = NEGS, v2 = NEGS;
    __shared__ float h1[2][16], h2[2][16];
    for (int d = 2; d <= NN + MM; ++d) {
        __syncthreads();
        float s1 = __shfl_up(v1, 1);
        float s2 = __shfl_up(v2, 1);
        if (lane == 0) {
            if (i == 0) { s1 = NEGS; s2 = (d == 2) ? 0.0f : NEGS; }
            else { s1 = h1[(d - 1) & 1][wave - 1]; s2 = h2[(d - 1) & 1][wave - 1]; }
        }
        float nv = NEGS;
        if (d >= i0 + 2 && d <= i0 + 1088) {          // wave has >=1 valid lane
            const int j = d - i - 2;
            const bool valid = (j >= 0) && (j < MM);
            float th = blk.x;
            float up = s1 + Ac;
            float lf = v1 + Ac;
            float mx = fmaxf(fmaxf(up, s2), lf);      // v_max3_f32
            float ss = exp2f(up - mx) + exp2f(s2 - mx) + exp2f(lf - mx);
            float val = fmaf(th, LOG2E, mx + log2f(ss));
            nv = valid ? val : NEGS;
            if (valid) {
                if ((j & 3) == 3) {
                    blk = nblk;
                    if (j + 5 < MM) nblk = *(const float4*)(row + j + 5);
                } else {
                    blk.x = blk.y; blk.y = blk.z; blk.z = blk.w;
                }
            }
        }
        if (lane == 63) { h1[d & 1][wave] = nv; h2[d & 1][wave] = v1; }
        v2 = v1; v1 = nv;
    }
    if (i == NN - 1) out[b] = v1 * LN2f;
}

// ---------------------------------------------------------------- launcher
extern "C" void kernel_launch(void* const* d_in, const int* in_sizes, int n_in,
                              void* d_out, int out_size, void* d_ws, size_t ws_size,
                              hipStream_t stream) {
    const float* zx    = (const float*)d_in[0];
    const float* zy    = (const float*)d_in[1];
    const float* gw    = (const float*)d_in[2];
    const float* gapb  = (const float*)d_in[3];
    float* out = (float*)d_out;

    char* ws = (char*)d_ws;
    float*  theta = (float*)ws;                                  // 67,108,864 B
    __bf16* zxb   = (__bf16*)(ws + (size_t)67108864);            // 16,777,216 B
    __bf16* zyb   = (__bf16*)(ws + (size_t)67108864 + 16777216); // 16,777,216 B
    float*  acc   = (float*)(ws + (size_t)67108864 + 2 * 16777216);

    zero_acc<<<1, 64, 0, stream>>>(acc);
    conv_reduce<<<dim3(16, BATCH, 2), 256, 0, stream>>>(zx, zy, gw, zxb, zyb, acc);
    gemm_bt<<<dim3(MM / 64, NN / 64, BATCH), 256, 0, stream>>>(zxb, zyb, theta);
    nw_dp<<<BATCH, 1024, 0, stream>>>(theta, acc, gapb, out);
}

// Round 4
// 823.523 us; speedup vs baseline: 1.9518x; 1.9518x over previous
//
#include <hip/hip_runtime.h>
#include <hip/hip_bf16.h>

#define BATCH 16
#define NN 1024
#define MM 1024
#define DD 512

#define LOG2E 1.4426950408889634f
#define LN2f  0.6931471805599453f
#define NEGS  -1.442695e9f   // NEG (-1e9) scaled by log2e; acts as -inf sentinel

typedef __bf16 v8bf __attribute__((ext_vector_type(8)));
typedef __bf16 v4bf __attribute__((ext_vector_type(4)));
typedef float  v4f  __attribute__((ext_vector_type(4)));

// ---------------------------------------------------------------- zero A acc
__global__ void zero_acc(float* a) {
    if (threadIdx.x < BATCH) a[threadIdx.x] = 0.0f;
}

// ------------------------------------------- fp32->bf16 convert + gap-dot
__global__ __launch_bounds__(256) void conv_reduce(
        const float* __restrict__ zx, const float* __restrict__ zy,
        const float* __restrict__ gw,
        __bf16* __restrict__ zxb, __bf16* __restrict__ zyb,
        float* __restrict__ acc) {
    const int chunk = blockIdx.x, b = blockIdx.y, which = blockIdx.z;
    const float* src = which ? zy : zx;
    __bf16* dst = which ? zyb : zxb;
    const float* g = gw + which * DD;
    const size_t base = ((size_t)b * NN + (size_t)chunk * 64) * DD;
    const int t = threadIdx.x;
    const int col = (t * 4) & (DD - 1);
    const float4 gv = *(const float4*)(g + col);
    float sum = 0.0f;
    #pragma unroll 4
    for (int it = 0; it < 32; ++it) {
        size_t off = base + (size_t)it * 1024 + t * 4;
        float4 x = *(const float4*)(src + off);
        sum += x.x * gv.x + x.y * gv.y + x.z * gv.z + x.w * gv.w;
        v4bf o = { (__bf16)x.x, (__bf16)x.y, (__bf16)x.z, (__bf16)x.w };
        *(v4bf*)(dst + off) = o;
    }
    #pragma unroll
    for (int o = 32; o > 0; o >>= 1) sum += __shfl_down(sum, o);
    __shared__ float wsum[4];
    if ((t & 63) == 0) wsum[t >> 6] = sum;
    __syncthreads();
    if (t == 0) {
        float s = wsum[0] + wsum[1] + wsum[2] + wsum[3];
        atomicAdd(acc + b, s * (1.0f / 1024.0f));
    }
}

// ------------------------------------------------------- bf16 MFMA NT GEMM
// out[row i][col j] = sum_d A[i,d]*B[j,d].  Called with A=zyb, B=zxb so the
// output buffer is thetaT[j_theta][i_theta] (theta transposed) at zero cost.
__global__ __launch_bounds__(256) void gemm_bt(
        const __bf16* __restrict__ Abf, const __bf16* __restrict__ Bbf,
        float* __restrict__ theta) {
    __shared__ __bf16 As[64 * 40];
    __shared__ __bf16 Bs[64 * 40];
    const int b = blockIdx.z;
    const int i0 = blockIdx.y * 64, j0 = blockIdx.x * 64;
    const __bf16* ap = Abf + ((size_t)b * NN + i0) * DD;
    const __bf16* bp = Bbf + ((size_t)b * MM + j0) * DD;
    const int t = threadIdx.x;
    const int srow = t >> 2, scol = (t & 3) * 8;
    const int lane = t & 63, wave = t >> 6;
    const int mrow = lane & 15, quad = lane >> 4;
    v4f acc[4] = {};
    for (int kk = 0; kk < DD; kk += 32) {
        if (kk) __syncthreads();
        *(v8bf*)&As[srow * 40 + scol] = *(const v8bf*)(ap + (size_t)srow * DD + kk + scol);
        *(v8bf*)&Bs[srow * 40 + scol] = *(const v8bf*)(bp + (size_t)srow * DD + kk + scol);
        __syncthreads();
        v8bf af = *(const v8bf*)&As[(wave * 16 + mrow) * 40 + quad * 8];
        #pragma unroll
        for (int tt = 0; tt < 4; ++tt) {
            v8bf bf = *(const v8bf*)&Bs[(tt * 16 + mrow) * 40 + quad * 8];
            acc[tt] = __builtin_amdgcn_mfma_f32_16x16x32_bf16(af, bf, acc[tt], 0, 0, 0);
        }
    }
    const size_t tb = (size_t)b * NN * MM;
    #pragma unroll
    for (int tt = 0; tt < 4; ++tt) {
        int j = j0 + tt * 16 + mrow;
        #pragma unroll
        for (int r = 0; r < 4; ++r) {
            int i = i0 + wave * 16 + quad * 4 + r;
            theta[tb + (size_t)i * MM + j] = acc[tt][r];
        }
    }
}

// --------------------------------------------------- soft-NW wavefront DP
// ONE WAVE per batch, zero barriers. Lane t owns V-grid rows 16t+1..16t+16.
// Iteration s: lane t processes theta-column c = s - t (V-col jc = c+1) for
// all 16 of its rows, chained in-register. Cross-lane deps (lane t-1 bottom
// row at lag 1 and 2) via two shfl_up. thetaT gives each lane 16 contiguous
// floats per column, prefetched one iteration ahead.
__global__ __launch_bounds__(64) void nw_dp(
        const float* __restrict__ thetaT, const float* __restrict__ acc,
        const float* __restrict__ gap_b, float* __restrict__ out) {
    const int b = blockIdx.x;
    const int t = threadIdx.x;
    const float Ac = (acc[b] + gap_b[0]) * LOG2E;
    const float* Tb = thetaT + (size_t)b * NN * MM + t * 16;

    float v[16];
    #pragma unroll
    for (int k = 0; k < 16; ++k) v[k] = NEGS;
    float v15c = NEGS, v15p = NEGS;   // v[15] after iter s-1, s-2

    float4 cur[4], nxt[4];
    #pragma unroll
    for (int q = 0; q < 4; ++q) cur[q] = *(const float4*)(Tb + q * 4);  // col 0

    for (int s = 0; s < NN + 63; ++s) {
        float tc = __shfl_up(v15c, 1);   // V[16t][jc]
        float tp = __shfl_up(v15p, 1);   // V[16t][jc-1]
        if (t == 0) { tc = NEGS; tp = (s == 0) ? 0.0f : NEGS; }
        v15p = v15c;

        // prefetch next column
        int cn = s + 1 - t;
        cn = cn < 0 ? 0 : (cn > MM - 1 ? MM - 1 : cn);
        const float* pn = Tb + (size_t)cn * NN;
        #pragma unroll
        for (int q = 0; q < 4; ++q) nxt[q] = *(const float4*)(pn + q * 4);

        const int c = s - t;
        if (c >= 0 && c < MM) {
            const float* th = (const float*)cur;
            float up_in = tc;
            float dg = tp;
            #pragma unroll
            for (int k = 0; k < 16; ++k) {
                float left = v[k];
                float up = up_in + Ac;
                float lf = left + Ac;
                float mx = fmaxf(fmaxf(up, dg), lf);
                float ss = __builtin_amdgcn_exp2f(up - mx)
                         + __builtin_amdgcn_exp2f(dg - mx)
                         + __builtin_amdgcn_exp2f(lf - mx);
                float nv = fmaf(th[k], LOG2E, mx + __builtin_amdgcn_logf(ss));
                dg = left;      // next row's diag = V[ir][jc-1]
                up_in = nv;     // next row's up   = V[ir][jc]
                v[k] = nv;
            }
            v15c = v[15];
        }
        #pragma unroll
        for (int q = 0; q < 4; ++q) cur[q] = nxt[q];
    }
    if (t == 63) out[b] = v[15] * LN2f;
}

// ---------------------------------------------------------------- launcher
extern "C" void kernel_launch(void* const* d_in, const int* in_sizes, int n_in,
                              void* d_out, int out_size, void* d_ws, size_t ws_size,
                              hipStream_t stream) {
    const float* zx    = (const float*)d_in[0];
    const float* zy    = (const float*)d_in[1];
    const float* gw    = (const float*)d_in[2];
    const float* gapb  = (const float*)d_in[3];
    float* out = (float*)d_out;

    char* ws = (char*)d_ws;
    float*  thetaT = (float*)ws;                                  // 67,108,864 B
    __bf16* zxb   = (__bf16*)(ws + (size_t)67108864);             // 16,777,216 B
    __bf16* zyb   = (__bf16*)(ws + (size_t)67108864 + 16777216);  // 16,777,216 B
    float*  acc   = (float*)(ws + (size_t)67108864 + 2 * 16777216);

    zero_acc<<<1, 64, 0, stream>>>(acc);
    conv_reduce<<<dim3(16, BATCH, 2), 256, 0, stream>>>(zx, zy, gw, zxb, zyb, acc);
    // swapped args: output = theta^T
    gemm_bt<<<dim3(MM / 64, NN / 64, BATCH), 256, 0, stream>>>(zyb, zxb, thetaT);
    nw_dp<<<BATCH, 64, 0, stream>>>(thetaT, acc, gapb, out);
}

// Round 5
// 678.976 us; speedup vs baseline: 2.3673x; 1.2129x over previous
//
#include <hip/hip_runtime.h>
#include <hip/hip_bf16.h>

#define BATCH 16
#define NN 1024
#define MM 1024
#define DD 512

#define LOG2E 1.4426950408889634f
#define LN2f  0.6931471805599453f
#define NEGS  -1.442695e9f   // NEG (-1e9) scaled by log2e; acts as -inf sentinel

#define DSTAG 128                       // inter-wave column stagger
#define GTOT  (NN + 63 + 3 * DSTAG + 4) // 1475, padded; extra iters are no-ops

typedef __bf16 v8bf __attribute__((ext_vector_type(8)));
typedef __bf16 v4bf __attribute__((ext_vector_type(4)));
typedef float  v4f  __attribute__((ext_vector_type(4)));

// ---------------------------------------------------------------- zero A acc
__global__ void zero_acc(float* a) {
    if (threadIdx.x < BATCH) a[threadIdx.x] = 0.0f;
}

// ------------------------------------------- fp32->bf16 convert + gap-dot
__global__ __launch_bounds__(256) void conv_reduce(
        const float* __restrict__ zx, const float* __restrict__ zy,
        const float* __restrict__ gw,
        __bf16* __restrict__ zxb, __bf16* __restrict__ zyb,
        float* __restrict__ acc) {
    const int chunk = blockIdx.x, b = blockIdx.y, which = blockIdx.z;
    const float* src = which ? zy : zx;
    __bf16* dst = which ? zyb : zxb;
    const float* g = gw + which * DD;
    const size_t base = ((size_t)b * NN + (size_t)chunk * 64) * DD;
    const int t = threadIdx.x;
    const int col = (t * 4) & (DD - 1);
    const float4 gv = *(const float4*)(g + col);
    float sum = 0.0f;
    #pragma unroll 4
    for (int it = 0; it < 32; ++it) {
        size_t off = base + (size_t)it * 1024 + t * 4;
        float4 x = *(const float4*)(src + off);
        sum += x.x * gv.x + x.y * gv.y + x.z * gv.z + x.w * gv.w;
        v4bf o = { (__bf16)x.x, (__bf16)x.y, (__bf16)x.z, (__bf16)x.w };
        *(v4bf*)(dst + off) = o;
    }
    #pragma unroll
    for (int o = 32; o > 0; o >>= 1) sum += __shfl_down(sum, o);
    __shared__ float wsum[4];
    if ((t & 63) == 0) wsum[t >> 6] = sum;
    __syncthreads();
    if (t == 0) {
        float s = wsum[0] + wsum[1] + wsum[2] + wsum[3];
        atomicAdd(acc + b, s * (1.0f / 1024.0f));
    }
}

// ------------------------------------------------------- bf16 MFMA NT GEMM
// out[row i][col j] = sum_d A[i,d]*B[j,d].  Called with A=zyb, B=zxb so the
// output buffer is thetaT[j_theta][i_theta] (theta transposed) at zero cost.
__global__ __launch_bounds__(256) void gemm_bt(
        const __bf16* __restrict__ Abf, const __bf16* __restrict__ Bbf,
        float* __restrict__ theta) {
    __shared__ __bf16 As[64 * 40];
    __shared__ __bf16 Bs[64 * 40];
    const int b = blockIdx.z;
    const int i0 = blockIdx.y * 64, j0 = blockIdx.x * 64;
    const __bf16* ap = Abf + ((size_t)b * NN + i0) * DD;
    const __bf16* bp = Bbf + ((size_t)b * MM + j0) * DD;
    const int t = threadIdx.x;
    const int srow = t >> 2, scol = (t & 3) * 8;
    const int lane = t & 63, wave = t >> 6;
    const int mrow = lane & 15, quad = lane >> 4;
    v4f acc[4] = {};
    for (int kk = 0; kk < DD; kk += 32) {
        if (kk) __syncthreads();
        *(v8bf*)&As[srow * 40 + scol] = *(const v8bf*)(ap + (size_t)srow * DD + kk + scol);
        *(v8bf*)&Bs[srow * 40 + scol] = *(const v8bf*)(bp + (size_t)srow * DD + kk + scol);
        __syncthreads();
        v8bf af = *(const v8bf*)&As[(wave * 16 + mrow) * 40 + quad * 8];
        #pragma unroll
        for (int tt = 0; tt < 4; ++tt) {
            v8bf bf = *(const v8bf*)&Bs[(tt * 16 + mrow) * 40 + quad * 8];
            acc[tt] = __builtin_amdgcn_mfma_f32_16x16x32_bf16(af, bf, acc[tt], 0, 0, 0);
        }
    }
    const size_t tb = (size_t)b * NN * MM;
    #pragma unroll
    for (int tt = 0; tt < 4; ++tt) {
        int j = j0 + tt * 16 + mrow;
        #pragma unroll
        for (int r = 0; r < 4; ++r) {
            int i = i0 + wave * 16 + quad * 4 + r;
            theta[tb + (size_t)i * MM + j] = acc[tt][r];
        }
    }
}

// --------------------------------------------------- soft-NW wavefront DP
// 4 waves per batch (256 threads). Wave w owns V-rows 256w+1..256w+256,
// lane t owns 4 rows. Wave w is staggered DSTAG=128 columns behind wave w-1;
// boundary values cross waves via a 256-slot LDS ring, with a barrier every
// 64 iterations (write->read gap is exactly 64 iters => one barrier between).
// Ring reads are prefetched into registers AFTER the barrier so lane 0's
// critical path never touches LDS latency. Theta prefetch depth = 3 columns.
__global__ __launch_bounds__(256) void nw_dp(
        const float* __restrict__ thetaT, const float* __restrict__ acc,
        const float* __restrict__ gap_b, float* __restrict__ out) {
    const int b = blockIdx.x;
    const int tid = threadIdx.x;
    const int t = tid & 63, w = tid >> 6;
    const float Ac = (acc[b] + gap_b[0]) * LOG2E;
    const int row0 = w * 256 + t * 4;          // theta rows row0..row0+3
    const int off = w * DSTAG + t;             // lane's column lag
    const float* Tb = thetaT + (size_t)b * NN * MM + row0;

    __shared__ float ring[3][256];

    float v[4];
    v[0] = v[1] = v[2] = v[3] = NEGS;
    float v3c = NEGS, v3p = NEGS;              // bottom-row value, iter-1 / iter-2

    // theta pipeline: cur = col c, nxt = c+1, nx2 = c+2 (clamped)
    float4 cur = *(const float4*)(Tb);
    float4 nxt = cur, nx2 = cur;
    {
        int c1 = 1 - off; c1 = c1 < 0 ? 0 : c1;
        int c2 = 2 - off; c2 = c2 < 0 ? 0 : c2;
        nxt = *(const float4*)(Tb + (size_t)c1 * NN);
        nx2 = *(const float4*)(Tb + (size_t)c2 * NN);
    }
    float rtc = NEGS, rtp = NEGS;              // prefetched ring values (lane 0, w>0)

    for (int g = 0; g < GTOT; ++g) {
        const int c = g - off;
        float tc = __shfl_up(v3c, 1);
        float tp = __shfl_up(v3p, 1);
        if (t == 0) {
            if (w == 0) { tc = NEGS; tp = (c == 0) ? 0.0f : NEGS; }
            else        { tc = rtc;  tp = (c == 0) ? NEGS : rtp; }
        }
        v3p = v3c;

        // theta prefetch, 3 columns ahead
        int cn = g + 3 - off;
        cn = cn < 0 ? 0 : (cn > MM - 1 ? MM - 1 : cn);
        float4 nx3 = *(const float4*)(Tb + (size_t)cn * NN);

        if (c >= 0 && c < MM) {
            const float* th = (const float*)&cur;
            float up_in = tc, dg = tp;
            #pragma unroll
            for (int k = 0; k < 4; ++k) {
                float left = v[k];
                float up = up_in + Ac;
                float lf = left + Ac;
                float mx = fmaxf(fmaxf(up, dg), lf);
                float ss = __builtin_amdgcn_exp2f(up - mx)
                         + __builtin_amdgcn_exp2f(dg - mx)
                         + __builtin_amdgcn_exp2f(lf - mx);
                float nv = fmaf(th[k], LOG2E, mx + __builtin_amdgcn_logf(ss));
                dg = left;      // next row's diag = V[row][jc-1]
                up_in = nv;     // next row's up   = V[row][jc]
                v[k] = nv;
            }
            v3c = v[3];
            if (t == 63 && w < 3) ring[w][c & 255] = v[3];
        }
        cur = nxt; nxt = nx2; nx2 = nx3;

        if ((g & 63) == 63) __syncthreads();

        // ring prefetch for iteration g+1 (after the barrier: the producer's
        // write for column (g+1-off) happened exactly 64 iterations earlier,
        // so the barrier above orders it before this read).
        if (t == 0 && w > 0) {
            int cnx = g + 1 - off;
            rtc = ring[w - 1][cnx & 255];
            rtp = ring[w - 1][(cnx - 1) & 255];
        }
    }
    if (tid == 255) out[b] = v[3] * LN2f;
}

// ---------------------------------------------------------------- launcher
extern "C" void kernel_launch(void* const* d_in, const int* in_sizes, int n_in,
                              void* d_out, int out_size, void* d_ws, size_t ws_size,
                              hipStream_t stream) {
    const float* zx    = (const float*)d_in[0];
    const float* zy    = (const float*)d_in[1];
    const float* gw    = (const float*)d_in[2];
    const float* gapb  = (const float*)d_in[3];
    float* out = (float*)d_out;

    char* ws = (char*)d_ws;
    float*  thetaT = (float*)ws;                                  // 67,108,864 B
    __bf16* zxb   = (__bf16*)(ws + (size_t)67108864);             // 16,777,216 B
    __bf16* zyb   = (__bf16*)(ws + (size_t)67108864 + 16777216);  // 16,777,216 B
    float*  acc   = (float*)(ws + (size_t)67108864 + 2 * 16777216);

    zero_acc<<<1, 64, 0, stream>>>(acc);
    conv_reduce<<<dim3(16, BATCH, 2), 256, 0, stream>>>(zx, zy, gw, zxb, zyb, acc);
    // swapped args: output = theta^T
    gemm_bt<<<dim3(MM / 64, NN / 64, BATCH), 256, 0, stream>>>(zyb, zxb, thetaT);
    nw_dp<<<BATCH, 256, 0, stream>>>(thetaT, acc, gapb, out);
}

// Round 6
// 519.397 us; speedup vs baseline: 3.0946x; 1.3072x over previous
//
#include <hip/hip_runtime.h>
#include <hip/hip_bf16.h>

#define BATCH 16
#define NN 1024
#define MM 1024
#define DD 512

#define LOG2E 1.4426950408889634f
#define LN2f  0.6931471805599453f
#define NEGS  -1.442695e9f   // NEG (-1e9) scaled by log2e; acts as -inf sentinel

#define DSTAG 128             // inter-wave column stagger
#define GTOT  1480            // >= NN+63+3*DSTAG+1 = 1471, multiple of 8
#define PF    8               // theta prefetch depth (iterations)

typedef __bf16 v8bf __attribute__((ext_vector_type(8)));
typedef __bf16 v4bf __attribute__((ext_vector_type(4)));
typedef float  v4f  __attribute__((ext_vector_type(4)));

// ---------------------------------------------------------------- zero A acc
__global__ void zero_acc(float* a) {
    if (threadIdx.x < BATCH) a[threadIdx.x] = 0.0f;
}

// ------------------------------------------- fp32->bf16 convert + gap-dot
__global__ __launch_bounds__(256) void conv_reduce(
        const float* __restrict__ zx, const float* __restrict__ zy,
        const float* __restrict__ gw,
        __bf16* __restrict__ zxb, __bf16* __restrict__ zyb,
        float* __restrict__ acc) {
    const int chunk = blockIdx.x, b = blockIdx.y, which = blockIdx.z;
    const float* src = which ? zy : zx;
    __bf16* dst = which ? zyb : zxb;
    const float* g = gw + which * DD;
    const size_t base = ((size_t)b * NN + (size_t)chunk * 64) * DD;
    const int t = threadIdx.x;
    const int col = (t * 4) & (DD - 1);
    const float4 gv = *(const float4*)(g + col);
    float sum = 0.0f;
    #pragma unroll 4
    for (int it = 0; it < 32; ++it) {
        size_t off = base + (size_t)it * 1024 + t * 4;
        float4 x = *(const float4*)(src + off);
        sum += x.x * gv.x + x.y * gv.y + x.z * gv.z + x.w * gv.w;
        v4bf o = { (__bf16)x.x, (__bf16)x.y, (__bf16)x.z, (__bf16)x.w };
        *(v4bf*)(dst + off) = o;
    }
    #pragma unroll
    for (int o = 32; o > 0; o >>= 1) sum += __shfl_down(sum, o);
    __shared__ float wsum[4];
    if ((t & 63) == 0) wsum[t >> 6] = sum;
    __syncthreads();
    if (t == 0) {
        float s = wsum[0] + wsum[1] + wsum[2] + wsum[3];
        atomicAdd(acc + b, s * (1.0f / 1024.0f));
    }
}

// ------------------------------------------------------- bf16 MFMA NT GEMM
// out[row i][col j] = sum_d A[i,d]*B[j,d].  Called with A=zyb, B=zxb so the
// output buffer is thetaT[j_theta][i_theta] (theta transposed) at zero cost.
__global__ __launch_bounds__(256) void gemm_bt(
        const __bf16* __restrict__ Abf, const __bf16* __restrict__ Bbf,
        float* __restrict__ theta) {
    __shared__ __bf16 As[64 * 40];
    __shared__ __bf16 Bs[64 * 40];
    const int b = blockIdx.z;
    const int i0 = blockIdx.y * 64, j0 = blockIdx.x * 64;
    const __bf16* ap = Abf + ((size_t)b * NN + i0) * DD;
    const __bf16* bp = Bbf + ((size_t)b * MM + j0) * DD;
    const int t = threadIdx.x;
    const int srow = t >> 2, scol = (t & 3) * 8;
    const int lane = t & 63, wave = t >> 6;
    const int mrow = lane & 15, quad = lane >> 4;
    v4f acc[4] = {};
    for (int kk = 0; kk < DD; kk += 32) {
        if (kk) __syncthreads();
        *(v8bf*)&As[srow * 40 + scol] = *(const v8bf*)(ap + (size_t)srow * DD + kk + scol);
        *(v8bf*)&Bs[srow * 40 + scol] = *(const v8bf*)(bp + (size_t)srow * DD + kk + scol);
        __syncthreads();
        v8bf af = *(const v8bf*)&As[(wave * 16 + mrow) * 40 + quad * 8];
        #pragma unroll
        for (int tt = 0; tt < 4; ++tt) {
            v8bf bf = *(const v8bf*)&Bs[(tt * 16 + mrow) * 40 + quad * 8];
            acc[tt] = __builtin_amdgcn_mfma_f32_16x16x32_bf16(af, bf, acc[tt], 0, 0, 0);
        }
    }
    const size_t tb = (size_t)b * NN * MM;
    #pragma unroll
    for (int tt = 0; tt < 4; ++tt) {
        int j = j0 + tt * 16 + mrow;
        #pragma unroll
        for (int r = 0; r < 4; ++r) {
            int i = i0 + wave * 16 + quad * 4 + r;
            theta[tb + (size_t)i * MM + j] = acc[tt][r];
        }
    }
}

// --------------------------------------------------- soft-NW wavefront DP
// 4 waves per batch (256 threads). Wave w owns V-rows 256w+1..256w+256,
// lane t owns 4 rows. Wave w staggered DSTAG=128 cols behind wave w-1;
// boundary crosses waves via a 256-slot LDS ring, barrier every 64 iters
// (write->read gap is 64 iters => exactly one barrier between).
// Theta: 8-deep circular register prefetch (unroll-by-8) so each vmcnt wait
// targets a load issued ~8 iterations (~2000 cyc) earlier — HBM fully hidden.
__global__ __launch_bounds__(256) void nw_dp(
        const float* __restrict__ thetaT, const float* __restrict__ acc,
        const float* __restrict__ gap_b, float* __restrict__ out) {
    const int b = blockIdx.x;
    const int tid = threadIdx.x;
    const int t = tid & 63, w = tid >> 6;
    const float Ac = (acc[b] + gap_b[0]) * LOG2E;
    const int row0 = w * 256 + t * 4;          // theta rows row0..row0+3
    const int off = w * DSTAG + t;             // lane's column lag
    const float* Tb = thetaT + (size_t)b * NN * MM + row0;

    __shared__ float ring[3][256];

    float v[4];
    v[0] = v[1] = v[2] = v[3] = NEGS;
    float v3c = NEGS, v3p = NEGS;              // bottom-row value, iter-1 / iter-2

    float4 pf[PF];
    #pragma unroll
    for (int u = 0; u < PF; ++u) {
        int c0 = u - off;
        c0 = c0 < 0 ? 0 : (c0 > MM - 1 ? MM - 1 : c0);
        pf[u] = *(const float4*)(Tb + (size_t)c0 * NN);
    }
    float rtc = NEGS, rtp = NEGS;              // prefetched ring values (lane 0, w>0)

    for (int gg = 0; gg < GTOT; gg += PF) {
        #pragma unroll
        for (int u = 0; u < PF; ++u) {
            const int g = gg + u;
            const int c = g - off;
            float tc = __shfl_up(v3c, 1);
            float tp = __shfl_up(v3p, 1);
            if (t == 0) {
                if (w == 0) { tc = NEGS; tp = (c == 0) ? 0.0f : NEGS; }
                else        { tc = rtc;  tp = (c == 0) ? NEGS : rtp; }
            }
            v3p = v3c;

            const float4 cur = pf[u];
            // re-issue this slot: column g + PF - off
            int cn = g + PF - off;
            cn = cn < 0 ? 0 : (cn > MM - 1 ? MM - 1 : cn);
            pf[u] = *(const float4*)(Tb + (size_t)cn * NN);

            if (c >= 0 && c < MM) {
                const float* th = (const float*)&cur;
                float up_in = tc, dg = tp;
                #pragma unroll
                for (int k = 0; k < 4; ++k) {
                    float left = v[k];
                    float up = up_in + Ac;
                    float lf = left + Ac;
                    float mx = fmaxf(fmaxf(up, dg), lf);
                    float ss = __builtin_amdgcn_exp2f(up - mx)
                             + __builtin_amdgcn_exp2f(dg - mx)
                             + __builtin_amdgcn_exp2f(lf - mx);
                    float nv = fmaf(th[k], LOG2E, mx + __builtin_amdgcn_logf(ss));
                    dg = left;      // next row's diag = V[row][jc-1]
                    up_in = nv;     // next row's up   = V[row][jc]
                    v[k] = nv;
                }
                v3c = v[3];
                if (t == 63 && w < 3) ring[w][c & 255] = v[3];
            }

            if ((g & 63) == 63) __syncthreads();

            // ring prefetch for iteration g+1 (ordered by the barrier above:
            // producer wrote column g+1-off exactly 64 iterations earlier).
            if (t == 0 && w > 0) {
                int cnx = g + 1 - off;
                rtc = ring[w - 1][cnx & 255];
                rtp = ring[w - 1][(cnx - 1) & 255];
            }
        }
    }
    if (tid == 255) out[b] = v[3] * LN2f;
}

// ---------------------------------------------------------------- launcher
extern "C" void kernel_launch(void* const* d_in, const int* in_sizes, int n_in,
                              void* d_out, int out_size, void* d_ws, size_t ws_size,
                              hipStream_t stream) {
    const float* zx    = (const float*)d_in[0];
    const float* zy    = (const float*)d_in[1];
    const float* gw    = (const float*)d_in[2];
    const float* gapb  = (const float*)d_in[3];
    float* out = (float*)d_out;

    char* ws = (char*)d_ws;
    float*  thetaT = (float*)ws;                                  // 67,108,864 B
    __bf16* zxb   = (__bf16*)(ws + (size_t)67108864);             // 16,777,216 B
    __bf16* zyb   = (__bf16*)(ws + (size_t)67108864 + 16777216);  // 16,777,216 B
    float*  acc   = (float*)(ws + (size_t)67108864 + 2 * 16777216);

    zero_acc<<<1, 64, 0, stream>>>(acc);
    conv_reduce<<<dim3(16, BATCH, 2), 256, 0, stream>>>(zx, zy, gw, zxb, zyb, acc);
    // swapped args: output = theta^T
    gemm_bt<<<dim3(MM / 64, NN / 64, BATCH), 256, 0, stream>>>(zyb, zxb, thetaT);
    nw_dp<<<BATCH, 256, 0, stream>>>(thetaT, acc, gapb, out);
}